// Round 1
// baseline (6684.510 us; speedup 1.0000x reference)
//
#include <hip/hip_runtime.h>
#include <hip/hip_bf16.h>
#include <math.h>

#define S_LEN 2048
#define HD    2048
#define DHEAD 128
#define NH    16
#define NKVH  4
#define FDIM  4096
#define NE    8
#define KVW   (NKVH*DHEAD)   // 512

// ---------------- RMSNorm: out = x * rsqrt(mean(x^2)+eps) * w ----------------
__global__ __launch_bounds__(256) void rmsnorm_kernel(const float* __restrict__ x,
    const float* __restrict__ w, float* __restrict__ out) {
  int row = blockIdx.x;
  const float* xr = x + (size_t)row * HD;
  float ss = 0.f;
  for (int i = threadIdx.x; i < HD; i += 256) { float v = xr[i]; ss += v * v; }
  #pragma unroll
  for (int off = 32; off > 0; off >>= 1) ss += __shfl_xor(ss, off, 64);
  __shared__ float red[4];
  int lane = threadIdx.x & 63, wid = threadIdx.x >> 6;
  if (lane == 0) red[wid] = ss;
  __syncthreads();
  float tot = red[0] + red[1] + red[2] + red[3];
  float scale = rsqrtf(tot * (1.0f / HD) + 1e-5f);
  float* orow = out + (size_t)row * HD;
  for (int i = threadIdx.x; i < HD; i += 256) orow[i] = xr[i] * scale * w[i];
}

// ---------------- C[M,N] = A[M,K] @ B[N,K]^T (+ residual), optional dual-out --
__global__ __launch_bounds__(256) void gemm_abt(const float* __restrict__ A,
    const float* __restrict__ B, const float* __restrict__ residual,
    float* __restrict__ C, float* __restrict__ C2, int M, int N, int K) {
  __shared__ float As[16][68];
  __shared__ float Bs[16][68];
  int m0 = blockIdx.y * 64, n0 = blockIdx.x * 64;
  int tid = threadIdx.x;
  int lk = tid & 15, lm = tid >> 4;
  int tx = tid & 15, ty = tid >> 4;
  float acc[4][4] = {};
  for (int k0 = 0; k0 < K; k0 += 16) {
    #pragma unroll
    for (int i = 0; i < 4; i++) {
      int m = lm + i * 16;
      int gm = m0 + m, gn = n0 + m;
      As[lk][m] = (gm < M) ? A[(size_t)gm * K + k0 + lk] : 0.f;
      Bs[lk][m] = (gn < N) ? B[(size_t)gn * K + k0 + lk] : 0.f;
    }
    __syncthreads();
    #pragma unroll
    for (int kk = 0; kk < 16; kk++) {
      float a[4], b[4];
      #pragma unroll
      for (int i = 0; i < 4; i++) a[i] = As[kk][ty * 4 + i];
      #pragma unroll
      for (int j = 0; j < 4; j++) b[j] = Bs[kk][tx * 4 + j];
      #pragma unroll
      for (int i = 0; i < 4; i++)
        #pragma unroll
        for (int j = 0; j < 4; j++) acc[i][j] += a[i] * b[j];
    }
    __syncthreads();
  }
  #pragma unroll
  for (int i = 0; i < 4; i++) {
    int gm = m0 + ty * 4 + i;
    if (gm >= M) continue;
    #pragma unroll
    for (int j = 0; j < 4; j++) {
      int gn = n0 + tx * 4 + j;
      if (gn >= N) continue;
      float v = acc[i][j];
      if (residual) v += residual[(size_t)gm * N + gn];
      C[(size_t)gm * N + gn] = v;
      if (C2) C2[(size_t)gm * N + gn] = v;
    }
  }
}

// ---------------- RoPE in-place on q [S,16*128] and k [S,4*128] --------------
__global__ __launch_bounds__(256) void rope_kernel(float* __restrict__ q, float* __restrict__ k) {
  int s = blockIdx.x;
  const float LOG_THETA = 9.210340371976184f; // ln(10000)
  for (int i = threadIdx.x; i < (NH + NKVH) * 64; i += 256) {
    int h = i >> 6, d = i & 63;
    float invf = expf(-(float)d * (1.0f / 64.0f) * LOG_THETA);
    float ang = (float)s * invf;
    float sn, cs;
    sincosf(ang, &sn, &cs);
    float* base = (h < NH) ? (q + (size_t)s * HD + h * DHEAD)
                           : (k + (size_t)s * KVW + (h - NH) * DHEAD);
    float x0 = base[d], x1 = base[d + 64];
    base[d]      = x0 * cs - x1 * sn;
    base[d + 64] = x1 * cs + x0 * sn;
  }
}

// ---------------- Flash-style causal attention -------------------------------
#define QT 32
#define KT 32
__global__ __launch_bounds__(256) void attn_kernel(const float* __restrict__ q,
    const float* __restrict__ k, const float* __restrict__ v, float* __restrict__ out) {
  __shared__ __align__(16) float Qs[QT][132];
  __shared__ __align__(16) float Ks[KT][132];
  __shared__ __align__(16) float Vs[KT][132];
  int h = blockIdx.y, qt = blockIdx.x;
  int g = h >> 2;  // kv head (groups = 4)
  int tid = threadIdx.x;
  int ql = tid >> 3, ks = tid & 7;
  int lane = tid & 63;
  for (int idx = tid; idx < QT * DHEAD; idx += 256) {
    int r = idx >> 7, d = idx & 127;
    Qs[r][d] = q[(size_t)(qt * QT + r) * HD + h * DHEAD + d];
  }
  float4 acc[4] = {};
  float m_run = -1e30f, l_run = 0.f;
  int qg = qt * QT + ql;
  for (int kt = 0; kt <= qt; kt++) {
    __syncthreads();
    for (int idx = tid; idx < KT * DHEAD; idx += 256) {
      int r = idx >> 7, d = idx & 127;
      size_t src = (size_t)(kt * KT + r) * KVW + g * DHEAD + d;
      Ks[r][d] = k[src];
      Vs[r][d] = v[src];
    }
    __syncthreads();
    float s[4] = {0.f, 0.f, 0.f, 0.f};
    const float4* Q4 = (const float4*)&Qs[ql][0];
    #pragma unroll 8
    for (int d4 = 0; d4 < 32; d4++) {
      float4 qv = Q4[d4];
      #pragma unroll
      for (int jj = 0; jj < 4; jj++) {
        float4 kv = ((const float4*)&Ks[ks * 4 + jj][0])[d4];
        s[jj] += qv.x * kv.x + qv.y * kv.y + qv.z * kv.z + qv.w * kv.w;
      }
    }
    float mloc = -1e30f;
    #pragma unroll
    for (int jj = 0; jj < 4; jj++) {
      int kjg = kt * KT + ks * 4 + jj;
      s[jj] = (kjg <= qg) ? s[jj] * 0.088388347648318447f : -1e30f;
      mloc = fmaxf(mloc, s[jj]);
    }
    #pragma unroll
    for (int off = 1; off < 8; off <<= 1) mloc = fmaxf(mloc, __shfl_xor(mloc, off, 64));
    float m_new = fmaxf(m_run, mloc);
    float alpha = expf(m_run - m_new);
    float p[4], lloc = 0.f;
    #pragma unroll
    for (int jj = 0; jj < 4; jj++) { p[jj] = expf(s[jj] - m_new); lloc += p[jj]; }
    #pragma unroll
    for (int off = 1; off < 8; off <<= 1) lloc += __shfl_xor(lloc, off, 64);
    l_run = l_run * alpha + lloc;
    m_run = m_new;
    #pragma unroll
    for (int qi = 0; qi < 4; qi++) {
      acc[qi].x *= alpha; acc[qi].y *= alpha; acc[qi].z *= alpha; acc[qi].w *= alpha;
    }
    #pragma unroll
    for (int j = 0; j < 32; j++) {
      float pj = __shfl(p[j & 3], (lane & 56) | (j >> 2), 64);
      #pragma unroll
      for (int qi = 0; qi < 4; qi++) {
        float4 vv = ((const float4*)&Vs[j][0])[ks * 4 + qi];
        acc[qi].x += pj * vv.x; acc[qi].y += pj * vv.y;
        acc[qi].z += pj * vv.z; acc[qi].w += pj * vv.w;
      }
    }
  }
  float inv_l = 1.0f / l_run;
  float4* o4 = (float4*)(out + (size_t)qg * HD + h * DHEAD + ks * 16);
  #pragma unroll
  for (int qi = 0; qi < 4; qi++) {
    float4 r;
    r.x = acc[qi].x * inv_l; r.y = acc[qi].y * inv_l;
    r.z = acc[qi].z * inv_l; r.w = acc[qi].w * inv_l;
    o4[qi] = r;
  }
}

// ---------------- MoE routing: logits -> softmax -> top2 ---------------------
__global__ __launch_bounds__(256) void route_kernel(const float* __restrict__ x2,
    const float* __restrict__ gw, int* __restrict__ tok_e, float* __restrict__ tok_w,
    int* __restrict__ counts) {
  int t = blockIdx.x;
  const float* xr = x2 + (size_t)t * HD;
  float acc[NE] = {};
  for (int i = threadIdx.x; i < HD; i += 256) {
    float xv = xr[i];
    #pragma unroll
    for (int e = 0; e < NE; e++) acc[e] += xv * gw[e * HD + i];
  }
  #pragma unroll
  for (int e = 0; e < NE; e++) {
    float vv = acc[e];
    #pragma unroll
    for (int off = 32; off > 0; off >>= 1) vv += __shfl_xor(vv, off, 64);
    acc[e] = vv;
  }
  __shared__ float red[4][NE];
  int lane = threadIdx.x & 63, wid = threadIdx.x >> 6;
  if (lane == 0) {
    #pragma unroll
    for (int e = 0; e < NE; e++) red[wid][e] = acc[e];
  }
  __syncthreads();
  if (threadIdx.x == 0) {
    float l[NE];
    float mx = -1e30f;
    #pragma unroll
    for (int e = 0; e < NE; e++) { l[e] = red[0][e] + red[1][e] + red[2][e] + red[3][e]; mx = fmaxf(mx, l[e]); }
    float ex[NE];
    #pragma unroll
    for (int e = 0; e < NE; e++) ex[e] = expf(l[e] - mx);
    int i0 = 0;
    #pragma unroll
    for (int e = 1; e < NE; e++) if (ex[e] > ex[i0]) i0 = e;
    int i1 = (i0 == 0) ? 1 : 0;
    #pragma unroll
    for (int e = 0; e < NE; e++) if (e != i0 && ex[e] > ex[i1]) i1 = e;
    float denom = ex[i0] + ex[i1];
    tok_e[2 * t] = i0; tok_e[2 * t + 1] = i1;
    tok_w[2 * t] = ex[i0] / denom; tok_w[2 * t + 1] = ex[i1] / denom;
    atomicAdd(&counts[i0], 1);
    atomicAdd(&counts[i1], 1);
  }
}

__global__ void zero_counts_kernel(int* counts) {
  if (threadIdx.x < NE) counts[threadIdx.x] = 0;
}

__global__ void offsets_kernel(const int* __restrict__ counts, int* __restrict__ offs,
                               int* __restrict__ ctr2) {
  if (threadIdx.x == 0) {
    int s = 0;
    for (int e = 0; e < NE; e++) { offs[e] = s; s += counts[e]; ctr2[e] = 0; }
  }
}

__global__ __launch_bounds__(256) void scatter_kernel(const int* __restrict__ tok_e,
    const float* __restrict__ tok_w, const int* __restrict__ offs, int* __restrict__ ctr2,
    int* __restrict__ slot_tok, float* __restrict__ slot_w) {
  int i = blockIdx.x * 256 + threadIdx.x;
  if (i >= 2 * S_LEN) return;
  int e = tok_e[i];
  int pos = offs[e] + atomicAdd(&ctr2[e], 1);
  slot_tok[pos] = i >> 1;
  slot_w[pos] = tok_w[i];
}

// ---------------- MoE stage 1: act = silu(x2@w1[e]^T) * (x2@w3[e]^T) ---------
__global__ __launch_bounds__(256) void moe1_kernel(const float* __restrict__ x2,
    const float* __restrict__ w1, const float* __restrict__ w3,
    const int* __restrict__ counts, const int* __restrict__ offs,
    const int* __restrict__ slot_tok, float* __restrict__ act) {
  int e = blockIdx.z;
  int ne = counts[e];
  int m0 = blockIdx.y * 64;
  if (m0 >= ne) return;
  int n0 = blockIdx.x * 64;
  __shared__ float As[16][68], B1s[16][68], B3s[16][68];
  __shared__ int toks[64];
  int tid = threadIdx.x;
  int base = offs[e];
  if (tid < 64) toks[tid] = (m0 + tid < ne) ? slot_tok[base + m0 + tid] : -1;
  __syncthreads();
  const float* W1 = w1 + (size_t)e * FDIM * HD;
  const float* W3 = w3 + (size_t)e * FDIM * HD;
  int lk = tid & 15, lm = tid >> 4;
  int tx = tid & 15, ty = tid >> 4;
  float acc1[4][4] = {}, acc3[4][4] = {};
  for (int k0 = 0; k0 < HD; k0 += 16) {
    #pragma unroll
    for (int i = 0; i < 4; i++) {
      int m = lm + i * 16;
      int tk = toks[m];
      As[lk][m] = (tk >= 0) ? x2[(size_t)tk * HD + k0 + lk] : 0.f;
      int gn = n0 + m;
      B1s[lk][m] = W1[(size_t)gn * HD + k0 + lk];
      B3s[lk][m] = W3[(size_t)gn * HD + k0 + lk];
    }
    __syncthreads();
    #pragma unroll
    for (int kk = 0; kk < 16; kk++) {
      float a[4], b1[4], b3[4];
      #pragma unroll
      for (int i = 0; i < 4; i++) a[i] = As[kk][ty * 4 + i];
      #pragma unroll
      for (int j = 0; j < 4; j++) { b1[j] = B1s[kk][tx * 4 + j]; b3[j] = B3s[kk][tx * 4 + j]; }
      #pragma unroll
      for (int i = 0; i < 4; i++)
        #pragma unroll
        for (int j = 0; j < 4; j++) {
          acc1[i][j] += a[i] * b1[j];
          acc3[i][j] += a[i] * b3[j];
        }
    }
    __syncthreads();
  }
  #pragma unroll
  for (int i = 0; i < 4; i++) {
    int gm = m0 + ty * 4 + i;
    if (gm >= ne) continue;
    float* arow = act + (size_t)(base + gm) * FDIM;
    #pragma unroll
    for (int j = 0; j < 4; j++) {
      int gn = n0 + tx * 4 + j;
      float gate = acc1[i][j];
      float val = gate / (1.f + expf(-gate)) * acc3[i][j];
      arow[gn] = val;
    }
  }
}

// ---------------- MoE stage 2: out[tok] += wt * (act @ w2[e]^T) --------------
__global__ __launch_bounds__(256) void moe2_kernel(const float* __restrict__ act,
    const float* __restrict__ w2, const int* __restrict__ counts, const int* __restrict__ offs,
    const int* __restrict__ slot_tok, const float* __restrict__ slot_w,
    float* __restrict__ out) {
  int e = blockIdx.z;
  int ne = counts[e];
  int m0 = blockIdx.y * 64;
  if (m0 >= ne) return;
  int n0 = blockIdx.x * 64;
  __shared__ float As[16][68], Bs[16][68];
  __shared__ int toks[64];
  __shared__ float wts[64];
  int tid = threadIdx.x;
  int base = offs[e];
  if (tid < 64) {
    bool valid = (m0 + tid < ne);
    toks[tid] = valid ? slot_tok[base + m0 + tid] : -1;
    wts[tid] = valid ? slot_w[base + m0 + tid] : 0.f;
  }
  __syncthreads();
  const float* W2 = w2 + (size_t)e * HD * FDIM;
  const float* Aseg = act + (size_t)base * FDIM;
  int lk = tid & 15, lm = tid >> 4;
  int tx = tid & 15, ty = tid >> 4;
  float acc[4][4] = {};
  for (int k0 = 0; k0 < FDIM; k0 += 16) {
    #pragma unroll
    for (int i = 0; i < 4; i++) {
      int m = lm + i * 16;
      As[lk][m] = (m0 + m < ne) ? Aseg[(size_t)(m0 + m) * FDIM + k0 + lk] : 0.f;
      Bs[lk][m] = W2[(size_t)(n0 + m) * FDIM + k0 + lk];
    }
    __syncthreads();
    #pragma unroll
    for (int kk = 0; kk < 16; kk++) {
      float a[4], b[4];
      #pragma unroll
      for (int i = 0; i < 4; i++) a[i] = As[kk][ty * 4 + i];
      #pragma unroll
      for (int j = 0; j < 4; j++) b[j] = Bs[kk][tx * 4 + j];
      #pragma unroll
      for (int i = 0; i < 4; i++)
        #pragma unroll
        for (int j = 0; j < 4; j++) acc[i][j] += a[i] * b[j];
    }
    __syncthreads();
  }
  #pragma unroll
  for (int i = 0; i < 4; i++) {
    int gm = m0 + ty * 4 + i;
    if (gm >= ne) continue;
    int tok = toks[ty * 4 + i];
    float wt = wts[ty * 4 + i];
    #pragma unroll
    for (int j = 0; j < 4; j++) {
      int gn = n0 + tx * 4 + j;
      atomicAdd(&out[(size_t)tok * HD + gn], wt * acc[i][j]);
    }
  }
}

// ---------------- launch -----------------------------------------------------
extern "C" void kernel_launch(void* const* d_in, const int* in_sizes, int n_in,
                              void* d_out, int out_size, void* d_ws, size_t ws_size,
                              hipStream_t stream) {
  const float* hidden = (const float*)d_in[0];
  const float* ln1_w  = (const float*)d_in[1];
  const float* ln2_w  = (const float*)d_in[2];
  const float* q_w    = (const float*)d_in[3];
  const float* k_w    = (const float*)d_in[4];
  const float* v_w    = (const float*)d_in[5];
  const float* o_w    = (const float*)d_in[6];
  const float* gate_w = (const float*)d_in[7];
  const float* w1     = (const float*)d_in[8];
  const float* w3     = (const float*)d_in[9];   // dict order: w1, w3, w2
  const float* w2     = (const float*)d_in[10];
  float* out = (float*)d_out;

  char* ws = (char*)d_ws;
  size_t off = 0;
  auto alloc = [&](size_t bytes) -> char* {
    char* p = ws + off;
    off += (bytes + 255) & ~(size_t)255;
    return p;
  };
  float* x    = (float*)alloc((size_t)S_LEN * HD * 4);          // rmsnorm1 out; reused as attn_out
  float* qb   = (float*)alloc((size_t)S_LEN * HD * 4);          // q; reused as x2
  float* kb   = (float*)alloc((size_t)S_LEN * KVW * 4);
  float* vb   = (float*)alloc((size_t)S_LEN * KVW * 4);
  float* hb   = (float*)alloc((size_t)S_LEN * HD * 4);          // residual-1 output
  float* act  = (float*)alloc((size_t)2 * S_LEN * FDIM * 4);    // 4096 x 4096
  int*   tok_e    = (int*)alloc(2 * S_LEN * 4);
  float* tok_w    = (float*)alloc(2 * S_LEN * 4);
  int*   slot_tok = (int*)alloc(2 * S_LEN * 4);
  float* slot_w   = (float*)alloc(2 * S_LEN * 4);
  int*   counts   = (int*)alloc(NE * 4);
  int*   offs     = (int*)alloc(NE * 4);
  int*   ctr2     = (int*)alloc(NE * 4);
  float* attn = x;
  float* x2   = qb;

  // --- attention block ---
  rmsnorm_kernel<<<S_LEN, 256, 0, stream>>>(hidden, ln1_w, x);
  gemm_abt<<<dim3(HD / 64, S_LEN / 64), 256, 0, stream>>>(x, q_w, nullptr, qb, nullptr, S_LEN, HD, HD);
  gemm_abt<<<dim3(KVW / 64, S_LEN / 64), 256, 0, stream>>>(x, k_w, nullptr, kb, nullptr, S_LEN, KVW, HD);
  gemm_abt<<<dim3(KVW / 64, S_LEN / 64), 256, 0, stream>>>(x, v_w, nullptr, vb, nullptr, S_LEN, KVW, HD);
  rope_kernel<<<S_LEN, 256, 0, stream>>>(qb, kb);
  attn_kernel<<<dim3(S_LEN / QT, NH), 256, 0, stream>>>(qb, kb, vb, attn);
  // h = hidden + attn @ o_w^T  (write both ws copy and d_out seed)
  gemm_abt<<<dim3(HD / 64, S_LEN / 64), 256, 0, stream>>>(attn, o_w, hidden, hb, out, S_LEN, HD, HD);

  // --- MoE block ---
  rmsnorm_kernel<<<S_LEN, 256, 0, stream>>>(hb, ln2_w, x2);
  zero_counts_kernel<<<1, 64, 0, stream>>>(counts);
  route_kernel<<<S_LEN, 256, 0, stream>>>(x2, gate_w, tok_e, tok_w, counts);
  offsets_kernel<<<1, 64, 0, stream>>>(counts, offs, ctr2);
  scatter_kernel<<<(2 * S_LEN + 255) / 256, 256, 0, stream>>>(tok_e, tok_w, offs, ctr2, slot_tok, slot_w);
  moe1_kernel<<<dim3(FDIM / 64, S_LEN / 64, NE), 256, 0, stream>>>(x2, w1, w3, counts, offs, slot_tok, act);
  moe2_kernel<<<dim3(HD / 64, S_LEN / 64, NE), 256, 0, stream>>>(act, w2, counts, offs, slot_tok, slot_w, out);
}